// Round 9
// baseline (243.089 us; speedup 1.0000x reference)
//
#include <hip/hip_runtime.h>
#include <hip/hip_bf16.h>
#include <stdint.h>

#define MROWS 32
#define LDA   264   // Abuf stride in bf16 elems: 528 B/row (16B-aligned, bank-skewed)
#define FMS   40    // fmA stride in bf16 elems (80 B, 16B-aligned)

typedef __bf16 bf16x8 __attribute__((ext_vector_type(8)));
typedef unsigned short u16x8 __attribute__((ext_vector_type(8)));
typedef float  f32x4  __attribute__((ext_vector_type(4)));
typedef float  f32x2  __attribute__((ext_vector_type(2)));

__device__ __forceinline__ unsigned short f2bf(float f) {
    union { float f; uint32_t u; } v; v.f = f;
    return (unsigned short)((v.u + 0x7FFFu + ((v.u >> 16) & 1u)) >> 16);
}

__device__ __forceinline__ ushort2 pk_bf16(float a, float b) {
    union { __hip_bfloat162 v; ushort2 u; } c;
    c.v = __float22bfloat162_rn(make_float2(a, b));
    return c.u;
}

// DPP row-reduction step on the VALU pipe (no DS): x += row_shr<N>(x),
// bound_ctrl=1 -> cross-row sources read 0 (sum identity). After steps
// 1,2,4,8 lane col==15 of each 16-lane row holds the full row sum.
template <int CTRL>
__device__ __forceinline__ float dpp_radd(float x) {
    union { float f; int i; } a, b;
    a.f = x;
    b.i = __builtin_amdgcn_update_dpp(0, a.i, CTRL, 0xF, 0xF, true);
    return x + b.f;
}
#define ROW_SHR1 0x111
#define ROW_SHR2 0x112
#define ROW_SHR4 0x114
#define ROW_SHR8 0x118
__device__ __forceinline__ float dpp_rowsum(float x) {
    x = dpp_radd<ROW_SHR1>(x);
    x = dpp_radd<ROW_SHR2>(x);
    x = dpp_radd<ROW_SHR4>(x);
    x = dpp_radd<ROW_SHR8>(x);
    return x;   // valid in lane col==15 of each row
}

// tanh-form GeLU via sigmoid on a float2 pair; muls/fmas lower to v_pk_* VOP3P.
__device__ __forceinline__ f32x2 gelu_fast2(f32x2 v) {
    const f32x2 t = v * v;
    f32x2 p = t * 0.044715f + 1.0f;
    const f32x2 u = v * p;
    f32x2 e;
    e.x = __builtin_amdgcn_exp2f(u.x * -2.3021131160186336f);  // exp(-2*0.79788456*u)
    e.y = __builtin_amdgcn_exp2f(u.y * -2.3021131160186336f);
    f32x2 r;
    r.x = __builtin_amdgcn_rcpf(1.0f + e.x);
    r.y = __builtin_amdgcn_rcpf(1.0f + e.y);
    return v * r;
}

// Fragment-order POSITION -> LOGICAL map: position f = w*64 + col*4 + j holds
// logical n = w*64 + j*16 + col.  NOT an involution (swaps a 4-bit and a
// 2-bit field).  Inverse is frag_inv below: frag_n(frag_inv(n)) == n.
__device__ __forceinline__ int frag_n(int f) {
    return (f & 0xC0) | ((f & 3) << 4) | ((f >> 2) & 15);
}
__device__ __forceinline__ int frag_inv(int n) {
    return (n & 0xC0) | ((n & 15) << 2) | ((n >> 4) & 3);
}

// ============================================================================
// prep_all (531 blocks, ONE launch, all sub-tasks dependency-free):
//  blk 0..499 : FHW = final_h @ (gamma*W1), 32 rows/block, MFMA GEMM with
//               B-fragments gamma-folded ON THE FLY from W1 global.
//               Natural-A x natural-B; C stored fragment-permuted.
//  blk 500..523: sqb[t] = step_q[t] + b_fm (fragment order, gather)
//  blk 524..527: wfmfrag (W_fm B-fragments, K=16 zero-padded to 32)
//  blk 528    : gw1f = colsum(gamma*W1), b1tf = colsum(beta*W1)+b1, w2f = W2
//  blk 529    : WFW = W_fm @ (gamma*W1) -> wfwfrag (bf16 B-fragments, gather)
//  blk 530    : SQW = (step_q+b_fm) @ (gamma*W1) -> sqwf (scatter via frag_inv)
// ============================================================================
__global__ __launch_bounds__(256) void prep_all(
    const float* __restrict__ final_h, const float* __restrict__ W1,
    const float* __restrict__ step_q,  const float* __restrict__ b_fm,
    const float* __restrict__ W_fm,    const float* __restrict__ gamma,
    const float* __restrict__ beta,    const float* __restrict__ b1,
    const float* __restrict__ W2,
    float* __restrict__ sqb,           unsigned short* __restrict__ wfmfrag,
    float* __restrict__ gw1f,          float* __restrict__ b1tf,
    float* __restrict__ w2f,           unsigned short* __restrict__ wfwfrag,
    float* __restrict__ sqwf,          float* __restrict__ FHW)
{
    __shared__ __align__(16) unsigned char smem[MROWS * LDA * 2];  // 16896 B
    const int blk = blockIdx.x, tid = threadIdx.x;

    if (blk < 500) {
        // ---- FHW GEMM block: rows R0..R0+31, NATURAL k-order (A and B both
        // natural; self-consistent without the frag permutation) ----
        unsigned short* Abuf = (unsigned short*)smem;
        const int w = tid >> 6, l = tid & 63;
        const int col = l & 15, qr = l >> 4;
        const int R0 = blk << 5;
        #pragma unroll
        for (int i = 0; i < 2; ++i) {
            #pragma unroll
            for (int r = 0; r < 4; ++r) {
                const int m = (i << 4) + (qr << 2) + r;
                const float* src = final_h + ((R0 + m) << 8) + (w << 6) + col;
                unsigned short* Ab = &Abuf[m * LDA + (w << 6) + col];
                const ushort2 p01 = pk_bf16(src[0],  src[16]);
                const ushort2 p23 = pk_bf16(src[32], src[48]);
                Ab[0] = p01.x; Ab[16] = p01.y; Ab[32] = p23.x; Ab[48] = p23.y;
            }
        }
        __syncthreads();
        f32x4 acc[2][4];
        #pragma unroll
        for (int i = 0; i < 2; ++i)
            #pragma unroll
            for (int j = 0; j < 4; ++j)
                acc[i][j] = (f32x4){0.f, 0.f, 0.f, 0.f};
        const int nb = (w << 6) + col;               // n for j=0
        #pragma unroll
        for (int kk = 0; kk < 8; ++kk) {
            const int k0 = (kk << 5) + (qr << 3);    // this lane's 8 k's
            float g[8];
            #pragma unroll
            for (int e = 0; e < 8; ++e) g[e] = gamma[k0 + e];
            const bf16x8 a0 = *(const bf16x8*)&Abuf[col * LDA + k0];
            const bf16x8 a1 = *(const bf16x8*)&Abuf[(16 + col) * LDA + k0];
            #pragma unroll
            for (int j = 0; j < 4; ++j) {
                const float* wp = W1 + k0 * 256 + nb + (j << 4);
                const ushort2 c0 = pk_bf16(wp[0]    * g[0], wp[256]  * g[1]);
                const ushort2 c1 = pk_bf16(wp[512]  * g[2], wp[768]  * g[3]);
                const ushort2 c2 = pk_bf16(wp[1024] * g[4], wp[1280] * g[5]);
                const ushort2 c3 = pk_bf16(wp[1536] * g[6], wp[1792] * g[7]);
                union { u16x8 u; bf16x8 b; } bv;
                bv.u[0] = c0.x; bv.u[1] = c0.y; bv.u[2] = c1.x; bv.u[3] = c1.y;
                bv.u[4] = c2.x; bv.u[5] = c2.y; bv.u[6] = c3.x; bv.u[7] = c3.y;
                acc[0][j] = __builtin_amdgcn_mfma_f32_16x16x32_bf16(a0, bv.b, acc[0][j], 0, 0, 0);
                acc[1][j] = __builtin_amdgcn_mfma_f32_16x16x32_bf16(a1, bv.b, acc[1][j], 0, 0, 0);
            }
        }
        // store fragment-permuted: position f = w*64+col*4+j holds n = frag_n(f)
        #pragma unroll
        for (int i = 0; i < 2; ++i) {
            #pragma unroll
            for (int r = 0; r < 4; ++r) {
                const int m = (i << 4) + (qr << 2) + r;
                float4 st;
                st.x = acc[i][0][r]; st.y = acc[i][1][r];
                st.z = acc[i][2][r]; st.w = acc[i][3][r];
                *(float4*)&FHW[((R0 + m) << 8) + (w << 6) + (col << 2)] = st;
            }
        }
    } else if (blk < 524) {
        const int t = blk - 500;
        const int n = frag_n(tid);
        sqb[t * 256 + tid] = step_q[t * 256 + n] + b_fm[n];
    } else if (blk < 528) {
        const int f  = blk - 524;                    // 0..3
        const int fr = (f << 8) + tid;
        const int l = fr & 63, j = (fr >> 6) & 3, w = fr >> 8;
        const int n = (w << 6) + (j << 4) + (l & 15);
        const int qr = l >> 4;
        #pragma unroll
        for (int e = 0; e < 8; ++e) {
            const int k = (qr << 3) + e;
            wfmfrag[(fr << 3) + e] = (k < 16) ? f2bf(W_fm[(k << 8) + n]) : (unsigned short)0;
        }
    } else if (blk == 528) {
        // gw1f/b1tf/w2f by direct colsum (gather pattern: read logical
        // n = frag_n(tid), store at position tid)
        const int n = frag_n(tid);
        float sg = 0.f, sb = 0.f;
        for (int k = 0; k < 256; ++k) {
            const float wv = W1[(k << 8) + n];
            sg = fmaf(gamma[k], wv, sg);
            sb = fmaf(beta[k],  wv, sb);
        }
        gw1f[tid] = sg;
        b1tf[tid] = sb + b1[n];
        w2f[tid]  = W2[n];
    } else if (blk == 529) {
        // WFW = W_fm @ (gamma*W1), then emit bf16 fragments (LDS staging,
        // gather pattern on the emit)
        float* WFWs = (float*)smem;                  // [16][256] = 16384 B
        float wfw[16];
        #pragma unroll
        for (int f = 0; f < 16; ++f) wfw[f] = 0.f;
        for (int h = 0; h < 256; ++h) {
            const float g1 = gamma[h] * W1[(h << 8) + tid];   // coalesced
            #pragma unroll
            for (int f = 0; f < 16; ++f)
                wfw[f] = fmaf(W_fm[(f << 8) + h], g1, wfw[f]);
        }
        #pragma unroll
        for (int f = 0; f < 16; ++f) WFWs[(f << 8) + tid] = wfw[f];
        __syncthreads();
        #pragma unroll
        for (int ff = 0; ff < 4; ++ff) {
            const int fr = (ff << 8) + tid;
            const int l = fr & 63, j = (fr >> 6) & 3, wq = fr >> 8;
            const int nn = (wq << 6) + (j << 4) + (l & 15);
            const int qr2 = l >> 4;
            #pragma unroll
            for (int e = 0; e < 8; ++e) {
                const int k = (qr2 << 3) + e;
                wfwfrag[(fr << 3) + e] = (k < 16) ? f2bf(WFWs[(k << 8) + nn]) : (unsigned short)0;
            }
        }
    } else {
        // SQW = (step_q + b_fm) @ (gamma*W1) -> sqwf (fragment order).
        // This thread computes LOGICAL column tid (coalesced W1 reads), so it
        // stores at the INVERSE position (frag_n(fpos) == tid) — r6's bug was
        // using frag_n here (not an involution).
        float sqw[24];
        #pragma unroll
        for (int t = 0; t < 24; ++t) sqw[t] = 0.f;
        float bsum = 0.f;
        for (int h = 0; h < 256; ++h) {
            const float g1 = gamma[h] * W1[(h << 8) + tid];   // coalesced
            bsum = fmaf(b_fm[h], g1, bsum);
            #pragma unroll
            for (int t = 0; t < 24; ++t)
                sqw[t] = fmaf(step_q[(t << 8) + h], g1, sqw[t]);
        }
        const int fpos = frag_inv(tid);
        #pragma unroll
        for (int t = 0; t < 24; ++t)
            sqwf[(t << 8) + fpos] = sqw[t] + bsum;
    }
}

// ============================================================================
// fused_head — r5-PASSING VERBATIM including __launch_bounds__(256, 6).
// Common-factor analysis r5(pass)/r6/r7/r8(fail ~0.18): the ONLY delta shared
// by all failures was (256,4); r5's VGPR=40 disproves the spill theory that
// motivated it. DO NOT change this attribute without a passing A/B.
// ============================================================================
__global__ __launch_bounds__(256, 6) void fused_head(
    const float* __restrict__ final_h, const float* __restrict__ future_met,
    const float* __restrict__ b2,      const float* __restrict__ sqb,
    const unsigned short* __restrict__ wfmfrag,
    const float* __restrict__ gw1f,    const float* __restrict__ b1tf,
    const float* __restrict__ w2f,     const unsigned short* __restrict__ wfwfrag,
    const float* __restrict__ sqwf,    const float* __restrict__ FHW,
    float* __restrict__ out)
{
    __shared__ __align__(16) unsigned short fmA[MROWS * FMS];   //  2560 B
    __shared__ float2 red[4][MROWS];                            //  1024 B
    __shared__ float2 mv[MROWS];                                //   256 B
    __shared__ float  part[4][MROWS];                           //   512 B

    const int tid = threadIdx.x;
    const int w   = tid >> 6;
    const int l   = tid & 63;
    const int col = l & 15;
    const int qr  = l >> 4;
    const int m0  = blockIdx.x * MROWS;
    const int bn0 = m0 / 24;            // one magic-div per thread
    const int tt0 = m0 - bn0 * 24;
    const int fb  = (w << 6) + (col << 2);   // fragment-table base for this thread

    // ---- stage fm rows as bf16 (k 0..15), zero-pad k 16..31 ----
    if (tid < 128) {
        const int row = tid >> 2, f0 = (tid & 3) << 2;
        const int tta = tt0 + row;
        const int sub = (tta >= 24) + (tta >= 48);
        const int tt  = tta - sub * 24;
        const int bn  = bn0 + sub;
        const int b   = bn / 1000, n = bn - b * 1000;
        const float4 v = *(const float4*)&future_met[((((b * 24 + tt) * 1000) + n) << 4) + f0];
        ushort2 lo = pk_bf16(v.x, v.y), hi = pk_bf16(v.z, v.w);
        ushort4 o; o.x = lo.x; o.y = lo.y; o.z = hi.x; o.w = hi.y;
        *(ushort4*)&fmA[row * FMS + f0] = o;
    }
    {
        const int row = tid >> 3, k = 16 + ((tid & 7) << 1);
        *(unsigned int*)&fmA[row * FMS + k] = 0u;
    }
    __syncthreads();

    // ---- phase A: x = final_h + (step_q + b_fm) + fm@W_fm (stats only) ----
    const int dlo = qr << 2;
    const int slo = ((tt0 + dlo) >= 24) + ((tt0 + dlo) >= 48);
    const int shi = ((tt0 + dlo + 19) >= 24) + ((tt0 + dlo + 19) >= 48);
    float flo[4], fhi[4];
    {
        const float* fhl = final_h + ((bn0 + slo) << 8) + (w << 6) + col;
        const float* fhh = final_h + ((bn0 + shi) << 8) + (w << 6) + col;
        #pragma unroll
        for (int j = 0; j < 4; ++j) { flo[j] = fhl[j << 4]; fhi[j] = fhh[j << 4]; }
    }

    f32x4 acc[2][4];
    #pragma unroll
    for (int i = 0; i < 2; ++i) {
        #pragma unroll
        for (int r = 0; r < 4; ++r) {
            const int d   = (i << 4) + (qr << 2) + r;
            const int tta = tt0 + d;
            const int sub = (tta >= 24) + (tta >= 48);
            const int tt  = tta - sub * 24;
            const bool lo = (sub == slo);
            const float4 sb4 = *(const float4*)&sqb[(tt << 8) + fb];
            acc[i][0][r] = (lo ? flo[0] : fhi[0]) + sb4.x;
            acc[i][1][r] = (lo ? flo[1] : fhi[1]) + sb4.y;
            acc[i][2][r] = (lo ? flo[2] : fhi[2]) + sb4.z;
            acc[i][3][r] = (lo ? flo[3] : fhi[3]) + sb4.w;
        }
    }
    // fm @ W_fm via MFMA (K=32, upper half zeros); af0/af1 reused in phase 2
    const bf16x8 af0 = *(const bf16x8*)&fmA[col * FMS + (qr << 3)];
    const bf16x8 af1 = *(const bf16x8*)&fmA[(16 + col) * FMS + (qr << 3)];
    {
        const unsigned short* Bwf = wfmfrag + (w << 11) + (l << 3);
        #pragma unroll
        for (int j = 0; j < 4; ++j) {
            const bf16x8 bf = *(const bf16x8*)(Bwf + (j << 9));
            acc[0][j] = __builtin_amdgcn_mfma_f32_16x16x32_bf16(af0, bf, acc[0][j], 0, 0, 0);
            acc[1][j] = __builtin_amdgcn_mfma_f32_16x16x32_bf16(af1, bf, acc[1][j], 0, 0, 0);
        }
    }

    // ---- stats (DPP row-sum on VALU pipe, raw x); x is then discarded ----
    #pragma unroll
    for (int i = 0; i < 2; ++i) {
        #pragma unroll
        for (int r = 0; r < 4; ++r) {
            const int m = (i << 4) + (qr << 2) + r;
            const f32x2 vA = {acc[i][0][r], acc[i][1][r]};
            const f32x2 vB = {acc[i][2][r], acc[i][3][r]};
            const f32x2 sv = vA + vB;                 // v_pk_add
            const f32x2 qv = vA * vA + vB * vB;       // v_pk_mul + v_pk_fma
            float s = sv.x + sv.y;
            float q = qv.x + qv.y;
            s = dpp_rowsum(s);                        // VALU, not DS
            q = dpp_rowsum(q);
            if (col == 15) red[w][m] = make_float2(s, q);
        }
    }
    __syncthreads();   // red ready

    if (tid < MROWS) {
        const float2 a0 = red[0][tid], a1 = red[1][tid], a2 = red[2][tid], a3 = red[3][tid];
        const float S = a0.x + a1.x + a2.x + a3.x;
        const float Q = a0.y + a1.y + a2.y + a3.y;
        const float mu = S * 0.00390625f;
        const float rstd = rsqrtf(Q * 0.00390625f - mu * mu + 1e-5f);
        mv[tid] = make_float2(mu, rstd);
    }

    // ---- phase 2: x@(gammaW1) = FHW[bn] + SQW[t] + fm@WFW (overlaps mv) ----
    #pragma unroll
    for (int i = 0; i < 2; ++i) {
        #pragma unroll
        for (int r = 0; r < 4; ++r) {
            const int d   = (i << 4) + (qr << 2) + r;
            const int tta = tt0 + d;
            const int sub = (tta >= 24) + (tta >= 48);
            const int tt  = tta - sub * 24;
            const float4 fw = *(const float4*)&FHW[((bn0 + sub) << 8) + fb];
            const float4 sw = *(const float4*)&sqwf[(tt << 8) + fb];
            acc[i][0][r] = fw.x + sw.x;
            acc[i][1][r] = fw.y + sw.y;
            acc[i][2][r] = fw.z + sw.z;
            acc[i][3][r] = fw.w + sw.w;
        }
    }
    {
        const unsigned short* Bw2 = wfwfrag + (w << 11) + (l << 3);
        #pragma unroll
        for (int j = 0; j < 4; ++j) {
            const bf16x8 bfv = *(const bf16x8*)(Bw2 + (j << 9));
            acc[0][j] = __builtin_amdgcn_mfma_f32_16x16x32_bf16(af0, bfv, acc[0][j], 0, 0, 0);
            acc[1][j] = __builtin_amdgcn_mfma_f32_16x16x32_bf16(af1, bfv, acc[1][j], 0, 0, 0);
        }
    }

    // epilogue vector prefetch (fragment-order float4 tables), as packed pairs
    const float4 gw4 = *(const float4*)&gw1f[fb];
    const float4 bt4 = *(const float4*)&b1tf[fb];
    const float4 w24 = *(const float4*)&w2f[fb];
    const f32x2 gwA = {gw4.x, gw4.y}, gwB = {gw4.z, gw4.w};
    const f32x2 btA = {bt4.x, bt4.y}, btB = {bt4.z, bt4.w};
    const f32x2 w2A = {w24.x, w24.y}, w2B = {w24.z, w24.w};
    __syncthreads();   // mv visible to all waves

    // ---- epilogue: y = rstd*acc + (-mu*rstd)*gw1 + b1t; gelu; dot W2; DPP reduce ----
    #pragma unroll
    for (int i = 0; i < 2; ++i) {
        #pragma unroll
        for (int r = 0; r < 4; ++r) {
            const int m = (i << 4) + (qr << 2) + r;
            const float2 p = mv[m];
            const float cm = -p.x * p.y;
            const f32x2 baseA = gwA * cm + btA;       // v_pk_fma
            const f32x2 baseB = gwB * cm + btB;
            const f32x2 accA = {acc[i][0][r], acc[i][1][r]};
            const f32x2 accB = {acc[i][2][r], acc[i][3][r]};
            const f32x2 yA = accA * p.y + baseA;      // v_pk_fma
            const f32x2 yB = accB * p.y + baseB;
            const f32x2 gvA = gelu_fast2(yA);
            const f32x2 gvB = gelu_fast2(yB);
            const f32x2 pp2 = gvA * w2A + gvB * w2B;  // v_pk_mul + v_pk_fma
            float pp = pp2.x + pp2.y;
            pp = dpp_rowsum(pp);                      // VALU, not DS
            if (col == 15) part[w][m] = pp;
        }
    }
    __syncthreads();

    if (tid < MROWS) {
        const int m = m0 + tid;
        const float val = part[0][tid] + part[1][tid] + part[2][tid] + part[3][tid] + b2[0];
        const int bn = m / 24, tt = m - bn * 24;
        const int b  = bn / 1000, n = bn - b * 1000;
        out[(b * 24 + tt) * 1000 + n] = val;
    }
}

// ============================================================================
// Fallback path (workspace too small for FHW): r3 kernels, proven at 199 us.
// ============================================================================
__global__ __launch_bounds__(256) void prep1_fb(const float* __restrict__ W1,
                                                const float* __restrict__ step_q,
                                                const float* __restrict__ b_fm,
                                                const float* __restrict__ W_fm,
                                                const float* __restrict__ gamma,
                                                const float* __restrict__ beta,
                                                unsigned short* __restrict__ w1frag,
                                                float* __restrict__ sqb,
                                                unsigned short* __restrict__ wfmfrag,
                                                float* __restrict__ gpart,
                                                float* __restrict__ bpart) {
    __shared__ unsigned short T[256][40];
    const int blk = blockIdx.x, tid = threadIdx.x;
    if (blk < 8) {
        const int kk = blk;
        float sg = 0.f, sb = 0.f;
        #pragma unroll
        for (int r = 0; r < 32; ++r) {
            const int klog = frag_n((kk << 5) + r);
            const float wv = W1[klog * 256 + tid];
            const float gv = gamma[klog];
            sg = fmaf(gv, wv, sg);
            sb = fmaf(beta[klog], wv, sb);
            T[tid][r] = f2bf(wv * gv);
        }
        gpart[(kk << 8) + tid] = sg;
        bpart[(kk << 8) + tid] = sb;
        __syncthreads();
        #pragma unroll
        for (int f = 0; f < 4; ++f) {
            const int fi = (f << 8) + tid;
            const int l = fi & 63, j = (fi >> 6) & 3, w = fi >> 8;
            const int n = (w << 6) + (j << 4) + (l & 15);
            const uint4 v = *(const uint4*)&T[n][(l >> 4) << 3];
            *(uint4*)&w1frag[((w << 5) + (j << 3) + kk) * 512 + (l << 3)] = v;
        }
    } else if (blk < 32) {
        const int t = blk - 8;
        const int n = frag_n(tid);
        sqb[t * 256 + tid] = step_q[t * 256 + n] + b_fm[n];
    } else {
        const int f  = blk - 32;
        const int fr = (f << 8) + tid;
        const int l = fr & 63, j = (fr >> 6) & 3, w = fr >> 8;
        const int n = (w << 6) + (j << 4) + (l & 15);
        const int qr = l >> 4;
        #pragma unroll
        for (int e = 0; e < 8; ++e) {
            const int k = (qr << 3) + e;
            wfmfrag[(fr << 3) + e] = (k < 16) ? f2bf(W_fm[(k << 8) + n]) : (unsigned short)0;
        }
    }
}

__global__ __launch_bounds__(256) void prep2_fb(const float* __restrict__ gpart,
                                                const float* __restrict__ bpart,
                                                const float* __restrict__ b1,
                                                const float* __restrict__ W2,
                                                float* __restrict__ gw1f,
                                                float* __restrict__ b1tf,
                                                float* __restrict__ w2f) {
    const int tid = threadIdx.x;
    const int n = frag_n(tid);
    float sg = 0.f, sb = 0.f;
    #pragma unroll
    for (int kk = 0; kk < 8; ++kk) {
        sg += gpart[(kk << 8) + n];
        sb += bpart[(kk << 8) + n];
    }
    gw1f[tid] = sg;
    b1tf[tid] = sb + b1[n];
    w2f[tid]  = W2[n];
}

__global__ __launch_bounds__(256, 6) void fused_head_v3(
    const float* __restrict__ final_h, const float* __restrict__ future_met,
    const float* __restrict__ b2,      const unsigned short* __restrict__ w1frag,
    const float* __restrict__ sqb,     const unsigned short* __restrict__ wfmfrag,
    const float* __restrict__ gw1f,    const float* __restrict__ b1tf,
    const float* __restrict__ w2f,     float* __restrict__ out)
{
    __shared__ __align__(16) unsigned short Abuf[MROWS * LDA];
    __shared__ __align__(16) unsigned short fmA[MROWS * FMS];
    __shared__ float2 red[4][MROWS];
    __shared__ float2 mv[MROWS];
    __shared__ float  part[4][MROWS];

    const int tid = threadIdx.x;
    const int w   = tid >> 6;
    const int l   = tid & 63;
    const int col = l & 15;
    const int qr  = l >> 4;
    const int m0  = blockIdx.x * MROWS;
    const int bn0 = m0 / 24;
    const int tt0 = m0 - bn0 * 24;
    const int fb  = (w << 6) + (col << 2);

    if (tid < 128) {
        const int row = tid >> 2, f0 = (tid & 3) << 2;
        const int tta = tt0 + row;
        const int sub = (tta >= 24) + (tta >= 48);
        const int tt  = tta - sub * 24;
        const int bn  = bn0 + sub;
        const int b   = bn / 1000, n = bn - b * 1000;
        const float4 v = *(const float4*)&future_met[((((b * 24 + tt) * 1000) + n) << 4) + f0];
        ushort2 lo = pk_bf16(v.x, v.y), hi = pk_bf16(v.z, v.w);
        ushort4 o; o.x = lo.x; o.y = lo.y; o.z = hi.x; o.w = hi.y;
        *(ushort4*)&fmA[row * FMS + f0] = o;
    }
    {
        const int row = tid >> 3, k = 16 + ((tid & 7) << 1);
        *(unsigned int*)&fmA[row * FMS + k] = 0u;
    }
    __syncthreads();

    const int dlo = qr << 2;
    const int slo = ((tt0 + dlo) >= 24) + ((tt0 + dlo) >= 48);
    const int shi = ((tt0 + dlo + 19) >= 24) + ((tt0 + dlo + 19) >= 48);
    float flo[4], fhi[4];
    {
        const float* fhl = final_h + ((bn0 + slo) << 8) + (w << 6) + col;
        const float* fhh = final_h + ((bn0 + shi) << 8) + (w << 6) + col;
        #pragma unroll
        for (int j = 0; j < 4; ++j) { flo[j] = fhl[j << 4]; fhi[j] = fhh[j << 4]; }
    }

    f32x4 acc[2][4];
    #pragma unroll
    for (int i = 0; i < 2; ++i) {
        #pragma unroll
        for (int r = 0; r < 4; ++r) {
            const int d   = (i << 4) + (qr << 2) + r;
            const int tta = tt0 + d;
            const int sub = (tta >= 24) + (tta >= 48);
            const int tt  = tta - sub * 24;
            const bool lo = (sub == slo);
            const float4 sb4 = *(const float4*)&sqb[(tt << 8) + fb];
            acc[i][0][r] = (lo ? flo[0] : fhi[0]) + sb4.x;
            acc[i][1][r] = (lo ? flo[1] : fhi[1]) + sb4.y;
            acc[i][2][r] = (lo ? flo[2] : fhi[2]) + sb4.z;
            acc[i][3][r] = (lo ? flo[3] : fhi[3]) + sb4.w;
        }
    }
    {
        const bf16x8 af0 = *(const bf16x8*)&fmA[col * FMS + (qr << 3)];
        const bf16x8 af1 = *(const bf16x8*)&fmA[(16 + col) * FMS + (qr << 3)];
        const unsigned short* Bwf = wfmfrag + (w << 11) + (l << 3);
        #pragma unroll
        for (int j = 0; j < 4; ++j) {
            const bf16x8 bf = *(const bf16x8*)(Bwf + (j << 9));
            acc[0][j] = __builtin_amdgcn_mfma_f32_16x16x32_bf16(af0, bf, acc[0][j], 0, 0, 0);
            acc[1][j] = __builtin_amdgcn_mfma_f32_16x16x32_bf16(af1, bf, acc[1][j], 0, 0, 0);
        }
    }

    #pragma unroll
    for (int i = 0; i < 2; ++i) {
        #pragma unroll
        for (int r = 0; r < 4; ++r) {
            const int m = (i << 4) + (qr << 2) + r;
            const f32x2 vA = {acc[i][0][r], acc[i][1][r]};
            const f32x2 vB = {acc[i][2][r], acc[i][3][r]};
            const f32x2 sv = vA + vB;
            const f32x2 qv = vA * vA + vB * vB;
            float s = sv.x + sv.y;
            float q = qv.x + qv.y;
            const ushort2 p01 = pk_bf16(vA.x, vA.y);
            const ushort2 p23 = pk_bf16(vB.x, vB.y);
            s = dpp_rowsum(s);
            q = dpp_rowsum(q);
            if (col == 15) red[w][m] = make_float2(s, q);
            ushort4 o; o.x = p01.x; o.y = p01.y; o.z = p23.x; o.w = p23.y;
            *(ushort4*)&Abuf[m * LDA + (w << 6) + (col << 2)] = o;
        }
    }
    __syncthreads();

    if (tid < MROWS) {
        const float2 a0 = red[0][tid], a1 = red[1][tid], a2 = red[2][tid], a3 = red[3][tid];
        const float S = a0.x + a1.x + a2.x + a3.x;
        const float Q = a0.y + a1.y + a2.y + a3.y;
        const float mu = S * 0.00390625f;
        const float rstd = rsqrtf(Q * 0.00390625f - mu * mu + 1e-5f);
        mv[tid] = make_float2(mu, rstd);
    }

    #pragma unroll
    for (int i = 0; i < 2; ++i)
        #pragma unroll
        for (int j = 0; j < 4; ++j)
            acc[i][j] = (f32x4){0.f, 0.f, 0.f, 0.f};

    {
        const unsigned short* Bw  = w1frag + (w << 14) + (l << 3);
        const unsigned short* Ab0 = &Abuf[col * LDA + (qr << 3)];
        const unsigned short* Ab1 = &Abuf[(16 + col) * LDA + (qr << 3)];
        #pragma unroll
        for (int kk = 0; kk < 8; ++kk) {
            const bf16x8 a0 = *(const bf16x8*)(Ab0 + (kk << 5));
            const bf16x8 a1 = *(const bf16x8*)(Ab1 + (kk << 5));
            #pragma unroll
            for (int j = 0; j < 4; ++j) {
                const bf16x8 bf = *(const bf16x8*)(Bw + (j << 12) + (kk << 9));
                acc[0][j] = __builtin_amdgcn_mfma_f32_16x16x32_bf16(a0, bf, acc[0][j], 0, 0, 0);
                acc[1][j] = __builtin_amdgcn_mfma_f32_16x16x32_bf16(a1, bf, acc[1][j], 0, 0, 0);
            }
        }
    }

    const float4 gw4 = *(const float4*)&gw1f[fb];
    const float4 bt4 = *(const float4*)&b1tf[fb];
    const float4 w24 = *(const float4*)&w2f[fb];
    const f32x2 gwA = {gw4.x, gw4.y}, gwB = {gw4.z, gw4.w};
    const f32x2 btA = {bt4.x, bt4.y}, btB = {bt4.z, bt4.w};
    const f32x2 w2A = {w24.x, w24.y}, w2B = {w24.z, w24.w};
    __syncthreads();

    #pragma unroll
    for (int i = 0; i < 2; ++i) {
        #pragma unroll
        for (int r = 0; r < 4; ++r) {
            const int m = (i << 4) + (qr << 2) + r;
            const float2 p = mv[m];
            const float cm = -p.x * p.y;
            const f32x2 baseA = gwA * cm + btA;
            const f32x2 baseB = gwB * cm + btB;
            const f32x2 accA = {acc[i][0][r], acc[i][1][r]};
            const f32x2 accB = {acc[i][2][r], acc[i][3][r]};
            const f32x2 yA = accA * p.y + baseA;
            const f32x2 yB = accB * p.y + baseB;
            const f32x2 gvA = gelu_fast2(yA);
            const f32x2 gvB = gelu_fast2(yB);
            const f32x2 pp2 = gvA * w2A + gvB * w2B;
            float pp = pp2.x + pp2.y;
            pp = dpp_rowsum(pp);
            if (col == 15) part[w][m] = pp;
        }
    }
    __syncthreads();

    if (tid < MROWS) {
        const int m = m0 + tid;
        const float val = part[0][tid] + part[1][tid] + part[2][tid] + part[3][tid] + b2[0];
        const int bn = m / 24, tt = m - bn * 24;
        const int b  = bn / 1000, n = bn - b * 1000;
        out[(b * 24 + tt) * 1000 + n] = val;
    }
}

extern "C" void kernel_launch(void* const* d_in, const int* in_sizes, int n_in,
                              void* d_out, int out_size, void* d_ws, size_t ws_size,
                              hipStream_t stream) {
    const float* final_h    = (const float*)d_in[0];
    const float* future_met = (const float*)d_in[1];
    const float* step_q     = (const float*)d_in[2];
    const float* W_fm       = (const float*)d_in[3];
    const float* b_fm       = (const float*)d_in[4];
    const float* gamma      = (const float*)d_in[5];
    const float* beta       = (const float*)d_in[6];
    const float* W1         = (const float*)d_in[7];
    const float* b1         = (const float*)d_in[8];
    const float* W2         = (const float*)d_in[9];
    const float* b2         = (const float*)d_in[10];
    float* out = (float*)d_out;
    char* ws = (char*)d_ws;

    // ---- new-path workspace layout ----
    float*          sqb     = (float*)(ws);                          //  24576 B
    unsigned short* wfmfrag = (unsigned short*)(ws + 24576);         //  16384 B
    float*          gw1f    = (float*)(ws + 40960);                  //   1024 B
    float*          b1tf    = (float*)(ws + 41984);                  //   1024 B
    float*          w2f     = (float*)(ws + 43008);                  //   1024 B
    unsigned short* wfwfrag = (unsigned short*)(ws + 44032);         //  16384 B
    float*          sqwf    = (float*)(ws + 60416);                  //  24576 B
    float*          FHW     = (float*)(ws + 84992);                  // 16384000 B
    const size_t WS_NEEDED = 84992u + 16384000u;

    if (ws_size >= WS_NEEDED) {
        prep_all<<<531, 256, 0, stream>>>(final_h, W1, step_q, b_fm, W_fm, gamma,
                                          beta, b1, W2, sqb, wfmfrag,
                                          gw1f, b1tf, w2f, wfwfrag, sqwf, FHW);
        fused_head<<<12000, 256, 0, stream>>>(final_h, future_met, b2, sqb, wfmfrag,
                                              gw1f, b1tf, w2f, wfwfrag, sqwf, FHW, out);
    } else {
        // ---- fallback (r3) layout + path ----
        unsigned short* w1frag_f  = (unsigned short*)(ws);           // 131072 B
        float*          sqb_f     = (float*)(ws + 131072);           //  24576 B
        unsigned short* wfmfrag_f = (unsigned short*)(ws + 155648);  //  16384 B
        float*          gpart_f   = (float*)(ws + 172032);           //   8192 B
        float*          bpart_f   = (float*)(ws + 180224);           //   8192 B
        float*          gw1f_f    = (float*)(ws + 188416);           //   1024 B
        float*          b1tf_f    = (float*)(ws + 189440);           //   1024 B
        float*          w2f_f     = (float*)(ws + 190464);           //   1024 B
        prep1_fb<<<36, 256, 0, stream>>>(W1, step_q, b_fm, W_fm, gamma, beta,
                                         w1frag_f, sqb_f, wfmfrag_f, gpart_f, bpart_f);
        prep2_fb<<<1, 256, 0, stream>>>(gpart_f, bpart_f, b1, W2, gw1f_f, b1tf_f, w2f_f);
        fused_head_v3<<<12000, 256, 0, stream>>>(final_h, future_met, b2, w1frag_f, sqb_f,
                                                 wfmfrag_f, gw1f_f, b1tf_f, w2f_f, out);
    }
}

// Round 10
// 226.574 us; speedup vs baseline: 1.0729x; 1.0729x over previous
//
#include <hip/hip_runtime.h>
#include <hip/hip_bf16.h>
#include <stdint.h>

#define MROWS 32
#define LDA   264   // Abuf stride in bf16 elems: 528 B/row (16B-aligned, bank-skewed)
#define FMS   40    // fmA stride in bf16 elems (80 B, 16B-aligned)

typedef __bf16 bf16x8 __attribute__((ext_vector_type(8)));
typedef float  f32x4  __attribute__((ext_vector_type(4)));
typedef float  f32x2  __attribute__((ext_vector_type(2)));

__device__ __forceinline__ unsigned short f2bf(float f) {
    union { float f; uint32_t u; } v; v.f = f;
    return (unsigned short)((v.u + 0x7FFFu + ((v.u >> 16) & 1u)) >> 16);
}

__device__ __forceinline__ ushort2 pk_bf16(float a, float b) {
    union { __hip_bfloat162 v; ushort2 u; } c;
    c.v = __float22bfloat162_rn(make_float2(a, b));
    return c.u;
}

// DPP row-reduction step on the VALU pipe (no DS): x += row_shr<N>(x),
// bound_ctrl=1 -> cross-row sources read 0 (sum identity). After steps
// 1,2,4,8 lane col==15 of each 16-lane row holds the full row sum.
template <int CTRL>
__device__ __forceinline__ float dpp_radd(float x) {
    union { float f; int i; } a, b;
    a.f = x;
    b.i = __builtin_amdgcn_update_dpp(0, a.i, CTRL, 0xF, 0xF, true);
    return x + b.f;
}
#define ROW_SHR1 0x111
#define ROW_SHR2 0x112
#define ROW_SHR4 0x114
#define ROW_SHR8 0x118
__device__ __forceinline__ float dpp_rowsum(float x) {
    x = dpp_radd<ROW_SHR1>(x);
    x = dpp_radd<ROW_SHR2>(x);
    x = dpp_radd<ROW_SHR4>(x);
    x = dpp_radd<ROW_SHR8>(x);
    return x;   // valid in lane col==15 of each row
}

// tanh-form GeLU via sigmoid on a float2 pair; muls/fmas lower to v_pk_* VOP3P.
__device__ __forceinline__ f32x2 gelu_fast2(f32x2 v) {
    const f32x2 t = v * v;
    f32x2 p = t * 0.044715f + 1.0f;
    const f32x2 u = v * p;
    f32x2 e;
    e.x = __builtin_amdgcn_exp2f(u.x * -2.3021131160186336f);  // exp(-2*0.79788456*u)
    e.y = __builtin_amdgcn_exp2f(u.y * -2.3021131160186336f);
    f32x2 r;
    r.x = __builtin_amdgcn_rcpf(1.0f + e.x);
    r.y = __builtin_amdgcn_rcpf(1.0f + e.y);
    return v * r;
}

// Fragment-order POSITION -> LOGICAL map: position f = w*64 + col*4 + j holds
// logical n = w*64 + j*16 + col.  NOT an involution.
__device__ __forceinline__ int frag_n(int f) {
    return (f & 0xC0) | ((f & 3) << 4) | ((f >> 2) & 15);
}

// prep1 (44 blocks new path / 36 fallback) — r5-PASSING VERBATIM.
// Converts W1 to w1frag ONCE (the r9 prep_all on-the-fly fold re-converted
// all of W1 per FHW block, 500x redundant -> prep_all was ~124 us).
__global__ __launch_bounds__(256) void prep1(const float* __restrict__ W1,
                                             const float* __restrict__ step_q,
                                             const float* __restrict__ b_fm,
                                             const float* __restrict__ W_fm,
                                             const float* __restrict__ gamma,
                                             const float* __restrict__ beta,
                                             unsigned short* __restrict__ w1frag,
                                             float* __restrict__ sqb,
                                             unsigned short* __restrict__ wfmfrag,
                                             float* __restrict__ gpart,
                                             float* __restrict__ bpart,
                                             float* __restrict__ WFWp,
                                             float* __restrict__ SQWp) {
    __shared__ unsigned short T[256][40];   // [n][k_local], rows 80B (16B-aligned)
    __shared__ float redw[8][32][41];       // prepW partials (padded)
    const int blk = blockIdx.x, tid = threadIdx.x;
    if (blk < 8) {
        const int kk = blk;
        float sg = 0.f, sb = 0.f;
        #pragma unroll
        for (int r = 0; r < 32; ++r) {
            const int klog = frag_n((kk << 5) + r);    // logical k for k-position kk*32+r
            const float wv = W1[klog * 256 + tid];     // coalesced row read (row uniform)
            const float gv = gamma[klog];
            sg = fmaf(gv, wv, sg);
            sb = fmaf(beta[klog], wv, sb);
            T[tid][r] = f2bf(wv * gv);                 // gamma folded into W1
        }
        gpart[(kk << 8) + tid] = sg;
        bpart[(kk << 8) + tid] = sb;
        __syncthreads();
        #pragma unroll
        for (int f = 0; f < 4; ++f) {
            const int fi = (f << 8) + tid;             // 0..1023 = w*256 + j*64 + l
            const int l = fi & 63, j = (fi >> 6) & 3, w = fi >> 8;
            const int n = (w << 6) + (j << 4) + (l & 15);
            const uint4 v = *(const uint4*)&T[n][(l >> 4) << 3];  // 8 contiguous bf16
            *(uint4*)&w1frag[((w << 5) + (j << 3) + kk) * 512 + (l << 3)] = v;
        }
    } else if (blk < 32) {
        const int t = blk - 8;
        const int n = frag_n(tid);
        sqb[t * 256 + tid] = step_q[t * 256 + n] + b_fm[n];
    } else if (blk < 36) {
        const int f  = blk - 32;                       // 0..3
        const int fr = (f << 8) + tid;
        const int l = fr & 63, j = (fr >> 6) & 3, w = fr >> 8;
        const int n = (w << 6) + (j << 4) + (l & 15);
        const int qr = l >> 4;
        #pragma unroll
        for (int e = 0; e < 8; ++e) {
            const int k = (qr << 3) + e;
            wfmfrag[(fr << 3) + e] = (k < 16) ? f2bf(W_fm[(k << 8) + n]) : (unsigned short)0;
        }
    } else {
        // prepW: 8 blocks x 32 cols; K split 8 ways across thread groups.
        const int kc = tid >> 5, cl = tid & 31;
        const int n  = ((blk - 36) << 5) + cl;
        float wfw[16];
        float sqw[24];
        #pragma unroll
        for (int f = 0; f < 16; ++f) wfw[f] = 0.f;
        #pragma unroll
        for (int t = 0; t < 24; ++t) sqw[t] = 0.f;
        for (int hh = 0; hh < 32; ++hh) {
            const int h = (kc << 5) + hh;
            const float g1 = gamma[h] * W1[(h << 8) + n];
            #pragma unroll
            for (int f = 0; f < 16; ++f)
                wfw[f] = fmaf(W_fm[(f << 8) + h], g1, wfw[f]);
            const float bf = b_fm[h];
            #pragma unroll
            for (int t = 0; t < 24; ++t)
                sqw[t] = fmaf(step_q[(t << 8) + h] + bf, g1, sqw[t]);
        }
        #pragma unroll
        for (int f = 0; f < 16; ++f) redw[kc][cl][f] = wfw[f];
        #pragma unroll
        for (int t = 0; t < 24; ++t) redw[kc][cl][16 + t] = sqw[t];
        __syncthreads();
        for (int e = tid; e < 1280; e += 256) {
            const int cl2 = e & 31, v = e >> 5;
            float s = 0.f;
            #pragma unroll
            for (int k2 = 0; k2 < 8; ++k2) s += redw[k2][cl2][v];
            const int nn = ((blk - 36) << 5) + cl2;
            if (v < 16) WFWp[(v << 8) + nn] = s;
            else        SQWp[((v - 16) << 8) + nn] = s;
        }
    }
}

// prep2 (fallback path only) — r5 verbatim.
__global__ __launch_bounds__(256) void prep2(const float* __restrict__ gpart,
                                             const float* __restrict__ bpart,
                                             const float* __restrict__ b1,
                                             const float* __restrict__ W2,
                                             float* __restrict__ gw1f,
                                             float* __restrict__ b1tf,
                                             float* __restrict__ w2f) {
    const int tid = threadIdx.x;
    const int n = frag_n(tid);
    float sg = 0.f, sb = 0.f;
    #pragma unroll
    for (int kk = 0; kk < 8; ++kk) {
        sg += gpart[(kk << 8) + n];
        sb += bpart[(kk << 8) + n];
    }
    gw1f[tid] = sg;
    b1tf[tid] = sb + b1[n];
    w2f[tid]  = W2[n];
}

// prep3 (1001 blocks): blocks 0..999 = FHW pre-GEMM (final_h @ gammaW1,
// r5-proven math, 16 rows/block for 2x block-parallelism vs r5's 32).
// Block 1000 = conversions (r5 verbatim).
__global__ __launch_bounds__(256) void prep3(const float* __restrict__ final_h,
                                             const unsigned short* __restrict__ w1frag,
                                             const float* __restrict__ gpart,
                                             const float* __restrict__ bpart,
                                             const float* __restrict__ b1,
                                             const float* __restrict__ W2,
                                             const float* __restrict__ WFWp,
                                             const float* __restrict__ SQWp,
                                             float* __restrict__ gw1f,
                                             float* __restrict__ b1tf,
                                             float* __restrict__ w2f,
                                             unsigned short* __restrict__ wfwfrag,
                                             float* __restrict__ sqwf,
                                             float* __restrict__ FHW) {
    __shared__ __align__(16) unsigned short Abuf[16 * LDA];   // 8448 B
    const int blk = blockIdx.x, tid = threadIdx.x;
    if (blk == 1000) {
        const int n = frag_n(tid);
        float sg = 0.f, sb = 0.f;
        #pragma unroll
        for (int kk = 0; kk < 8; ++kk) {
            sg += gpart[(kk << 8) + n];
            sb += bpart[(kk << 8) + n];
        }
        gw1f[tid] = sg;
        b1tf[tid] = sb + b1[n];
        w2f[tid]  = W2[n];
        #pragma unroll
        for (int f = 0; f < 4; ++f) {
            const int fr = (f << 8) + tid;
            const int l = fr & 63, j = (fr >> 6) & 3, wq = fr >> 8;
            const int nn = (wq << 6) + (j << 4) + (l & 15);
            const int qr2 = l >> 4;
            #pragma unroll
            for (int e = 0; e < 8; ++e) {
                const int k = (qr2 << 3) + e;
                wfwfrag[(fr << 3) + e] = (k < 16) ? f2bf(WFWp[(k << 8) + nn]) : (unsigned short)0;
            }
        }
        #pragma unroll
        for (int t = 0; t < 24; ++t)
            sqwf[(t << 8) + tid] = SQWp[(t << 8) + frag_n(tid)];
        return;
    }
    // ---- FHW GEMM block: rows R0..R0+15 (r5-proven frag-permuted A + w1frag B) ----
    const int w = tid >> 6, l = tid & 63;
    const int col = l & 15, qr = l >> 4;
    const int fb = (w << 6) + (col << 2);
    const int R0 = blk << 4;
    #pragma unroll
    for (int r = 0; r < 4; ++r) {
        const int m = (qr << 2) + r;
        const float* src = final_h + ((R0 + m) << 8) + (w << 6) + col;
        const ushort2 p01 = pk_bf16(src[0],  src[16]);
        const ushort2 p23 = pk_bf16(src[32], src[48]);
        ushort4 o; o.x = p01.x; o.y = p01.y; o.z = p23.x; o.w = p23.y;
        *(ushort4*)&Abuf[m * LDA + fb] = o;
    }
    __syncthreads();
    f32x4 acc[4];
    #pragma unroll
    for (int j = 0; j < 4; ++j)
        acc[j] = (f32x4){0.f, 0.f, 0.f, 0.f};
    {
        const unsigned short* Bw  = w1frag + (w << 14) + (l << 3);
        const unsigned short* Ab0 = &Abuf[col * LDA + (qr << 3)];
        #pragma unroll
        for (int kk = 0; kk < 8; ++kk) {
            const bf16x8 a0 = *(const bf16x8*)(Ab0 + (kk << 5));
            #pragma unroll
            for (int j = 0; j < 4; ++j) {
                const bf16x8 bf = *(const bf16x8*)(Bw + (j << 12) + (kk << 9));
                acc[j] = __builtin_amdgcn_mfma_f32_16x16x32_bf16(a0, bf, acc[j], 0, 0, 0);
            }
        }
    }
    #pragma unroll
    for (int r = 0; r < 4; ++r) {
        const int m = (qr << 2) + r;
        float4 st;
        st.x = acc[0][r]; st.y = acc[1][r];
        st.z = acc[2][r]; st.w = acc[3][r];
        *(float4*)&FHW[((R0 + m) << 8) + fb] = st;
    }
}

// ============================================================================
// fused_head — r9-PASSING VERBATIM with __launch_bounds__(256, 6).
// CONFIRMED A/B (r5,r9 pass / r6,r7,r8 fail ~0.18): (256,4) on this kernel
// corrupts results. DO NOT change this attribute.
// ============================================================================
__global__ __launch_bounds__(256, 6) void fused_head(
    const float* __restrict__ final_h, const float* __restrict__ future_met,
    const float* __restrict__ b2,      const float* __restrict__ sqb,
    const unsigned short* __restrict__ wfmfrag,
    const float* __restrict__ gw1f,    const float* __restrict__ b1tf,
    const float* __restrict__ w2f,     const unsigned short* __restrict__ wfwfrag,
    const float* __restrict__ sqwf,    const float* __restrict__ FHW,
    float* __restrict__ out)
{
    __shared__ __align__(16) unsigned short fmA[MROWS * FMS];   //  2560 B
    __shared__ float2 red[4][MROWS];                            //  1024 B
    __shared__ float2 mv[MROWS];                                //   256 B
    __shared__ float  part[4][MROWS];                           //   512 B

    const int tid = threadIdx.x;
    const int w   = tid >> 6;
    const int l   = tid & 63;
    const int col = l & 15;
    const int qr  = l >> 4;
    const int m0  = blockIdx.x * MROWS;
    const int bn0 = m0 / 24;            // one magic-div per thread
    const int tt0 = m0 - bn0 * 24;
    const int fb  = (w << 6) + (col << 2);   // fragment-table base for this thread

    // ---- stage fm rows as bf16 (k 0..15), zero-pad k 16..31 ----
    if (tid < 128) {
        const int row = tid >> 2, f0 = (tid & 3) << 2;
        const int tta = tt0 + row;
        const int sub = (tta >= 24) + (tta >= 48);
        const int tt  = tta - sub * 24;
        const int bn  = bn0 + sub;
        const int b   = bn / 1000, n = bn - b * 1000;
        const float4 v = *(const float4*)&future_met[((((b * 24 + tt) * 1000) + n) << 4) + f0];
        ushort2 lo = pk_bf16(v.x, v.y), hi = pk_bf16(v.z, v.w);
        ushort4 o; o.x = lo.x; o.y = lo.y; o.z = hi.x; o.w = hi.y;
        *(ushort4*)&fmA[row * FMS + f0] = o;
    }
    {
        const int row = tid >> 3, k = 16 + ((tid & 7) << 1);
        *(unsigned int*)&fmA[row * FMS + k] = 0u;
    }
    __syncthreads();

    // ---- phase A: x = final_h + (step_q + b_fm) + fm@W_fm (stats only) ----
    const int dlo = qr << 2;
    const int slo = ((tt0 + dlo) >= 24) + ((tt0 + dlo) >= 48);
    const int shi = ((tt0 + dlo + 19) >= 24) + ((tt0 + dlo + 19) >= 48);
    float flo[4], fhi[4];
    {
        const float* fhl = final_h + ((bn0 + slo) << 8) + (w << 6) + col;
        const float* fhh = final_h + ((bn0 + shi) << 8) + (w << 6) + col;
        #pragma unroll
        for (int j = 0; j < 4; ++j) { flo[j] = fhl[j << 4]; fhi[j] = fhh[j << 4]; }
    }

    f32x4 acc[2][4];
    #pragma unroll
    for (int i = 0; i < 2; ++i) {
        #pragma unroll
        for (int r = 0; r < 4; ++r) {
            const int d   = (i << 4) + (qr << 2) + r;
            const int tta = tt0 + d;
            const int sub = (tta >= 24) + (tta >= 48);
            const int tt  = tta - sub * 24;
            const bool lo = (sub == slo);
            const float4 sb4 = *(const float4*)&sqb[(tt << 8) + fb];
            acc[i][0][r] = (lo ? flo[0] : fhi[0]) + sb4.x;
            acc[i][1][r] = (lo ? flo[1] : fhi[1]) + sb4.y;
            acc[i][2][r] = (lo ? flo[2] : fhi[2]) + sb4.z;
            acc[i][3][r] = (lo ? flo[3] : fhi[3]) + sb4.w;
        }
    }
    // fm @ W_fm via MFMA (K=32, upper half zeros); af0/af1 reused in phase 2
    const bf16x8 af0 = *(const bf16x8*)&fmA[col * FMS + (qr << 3)];
    const bf16x8 af1 = *(const bf16x8*)&fmA[(16 + col) * FMS + (qr << 3)];
    {
        const unsigned short* Bwf = wfmfrag + (w << 11) + (l << 3);
        #pragma unroll
        for (int j = 0; j < 4; ++j) {
            const bf16x8 bf = *(const bf16x8*)(Bwf + (j << 9));
            acc[0][j] = __builtin_amdgcn_mfma_f32_16x16x32_bf16(af0, bf, acc[0][j], 0, 0, 0);
            acc[1][j] = __builtin_amdgcn_mfma_f32_16x16x32_bf16(af1, bf, acc[1][j], 0, 0, 0);
        }
    }

    // ---- stats (DPP row-sum on VALU pipe, raw x); x is then discarded ----
    #pragma unroll
    for (int i = 0; i < 2; ++i) {
        #pragma unroll
        for (int r = 0; r < 4; ++r) {
            const int m = (i << 4) + (qr << 2) + r;
            const f32x2 vA = {acc[i][0][r], acc[i][1][r]};
            const f32x2 vB = {acc[i][2][r], acc[i][3][r]};
            const f32x2 sv = vA + vB;                 // v_pk_add
            const f32x2 qv = vA * vA + vB * vB;       // v_pk_mul + v_pk_fma
            float s = sv.x + sv.y;
            float q = qv.x + qv.y;
            s = dpp_rowsum(s);                        // VALU, not DS
            q = dpp_rowsum(q);
            if (col == 15) red[w][m] = make_float2(s, q);
        }
    }
    __syncthreads();   // red ready

    if (tid < MROWS) {
        const float2 a0 = red[0][tid], a1 = red[1][tid], a2 = red[2][tid], a3 = red[3][tid];
        const float S = a0.x + a1.x + a2.x + a3.x;
        const float Q = a0.y + a1.y + a2.y + a3.y;
        const float mu = S * 0.00390625f;
        const float rstd = rsqrtf(Q * 0.00390625f - mu * mu + 1e-5f);
        mv[tid] = make_float2(mu, rstd);
    }

    // ---- phase 2: x@(gammaW1) = FHW[bn] + SQW[t] + fm@WFW (overlaps mv) ----
    #pragma unroll
    for (int i = 0; i < 2; ++i) {
        #pragma unroll
        for (int r = 0; r < 4; ++r) {
            const int d   = (i << 4) + (qr << 2) + r;
            const int tta = tt0 + d;
            const int sub = (tta >= 24) + (tta >= 48);
            const int tt  = tta - sub * 24;
            const float4 fw = *(const float4*)&FHW[((bn0 + sub) << 8) + fb];
            const float4 sw = *(const float4*)&sqwf[(tt << 8) + fb];
            acc[i][0][r] = fw.x + sw.x;
            acc[i][1][r] = fw.y + sw.y;
            acc[i][2][r] = fw.z + sw.z;
            acc[i][3][r] = fw.w + sw.w;
        }
    }
    {
        const unsigned short* Bw2 = wfwfrag + (w << 11) + (l << 3);
        #pragma unroll
        for (int j = 0; j < 4; ++j) {
            const bf16x8 bfv = *(const bf16x8*)(Bw2 + (j << 9));
            acc[0][j] = __builtin_amdgcn_mfma_f32_16x16x32_bf16(af0, bfv, acc[0][j], 0, 0, 0);
            acc[1][j] = __builtin_amdgcn_mfma_f32_16x16x32_bf16(af1, bfv, acc[1][j], 0, 0, 0);
        }
    }

    // epilogue vector prefetch (fragment-order float4 tables), as packed pairs
    const float4 gw4 = *(const float4*)&gw1f[fb];
    const float4 bt4 = *(const float4*)&b1tf[fb];
    const float4 w24 = *(const float4*)&w2f[fb];
    const f32x2 gwA = {gw4.x, gw4.y}, gwB = {gw4.z, gw4.w};
    const f32x2 btA = {bt4.x, bt4.y}, btB = {bt4.z, bt4.w};
    const f32x2 w2A = {w24.x, w24.y}, w2B = {w24.z, w24.w};
    __syncthreads();   // mv visible to all waves

    // ---- epilogue: y = rstd*acc + (-mu*rstd)*gw1 + b1t; gelu; dot W2; DPP reduce ----
    #pragma unroll
    for (int i = 0; i < 2; ++i) {
        #pragma unroll
        for (int r = 0; r < 4; ++r) {
            const int m = (i << 4) + (qr << 2) + r;
            const float2 p = mv[m];
            const float cm = -p.x * p.y;
            const f32x2 baseA = gwA * cm + btA;       // v_pk_fma
            const f32x2 baseB = gwB * cm + btB;
            const f32x2 accA = {acc[i][0][r], acc[i][1][r]};
            const f32x2 accB = {acc[i][2][r], acc[i][3][r]};
            const f32x2 yA = accA * p.y + baseA;      // v_pk_fma
            const f32x2 yB = accB * p.y + baseB;
            const f32x2 gvA = gelu_fast2(yA);
            const f32x2 gvB = gelu_fast2(yB);
            const f32x2 pp2 = gvA * w2A + gvB * w2B;  // v_pk_mul + v_pk_fma
            float pp = pp2.x + pp2.y;
            pp = dpp_rowsum(pp);                      // VALU, not DS
            if (col == 15) part[w][m] = pp;
        }
    }
    __syncthreads();

    if (tid < MROWS) {
        const int m = m0 + tid;
        const float val = part[0][tid] + part[1][tid] + part[2][tid] + part[3][tid] + b2[0];
        const int bn = m / 24, tt = m - bn * 24;
        const int b  = bn / 1000, n = bn - b * 1000;
        out[(b * 24 + tt) * 1000 + n] = val;
    }
}

// Fallback fused_head (r3 version, verbatim) for small workspaces.
__global__ __launch_bounds__(256, 6) void fused_head_v3(
    const float* __restrict__ final_h, const float* __restrict__ future_met,
    const float* __restrict__ b2,      const unsigned short* __restrict__ w1frag,
    const float* __restrict__ sqb,     const unsigned short* __restrict__ wfmfrag,
    const float* __restrict__ gw1f,    const float* __restrict__ b1tf,
    const float* __restrict__ w2f,     float* __restrict__ out)
{
    __shared__ __align__(16) unsigned short Abuf[MROWS * LDA];
    __shared__ __align__(16) unsigned short fmA[MROWS * FMS];
    __shared__ float2 red[4][MROWS];
    __shared__ float2 mv[MROWS];
    __shared__ float  part[4][MROWS];

    const int tid = threadIdx.x;
    const int w   = tid >> 6;
    const int l   = tid & 63;
    const int col = l & 15;
    const int qr  = l >> 4;
    const int m0  = blockIdx.x * MROWS;
    const int bn0 = m0 / 24;
    const int tt0 = m0 - bn0 * 24;
    const int fb  = (w << 6) + (col << 2);

    if (tid < 128) {
        const int row = tid >> 2, f0 = (tid & 3) << 2;
        const int tta = tt0 + row;
        const int sub = (tta >= 24) + (tta >= 48);
        const int tt  = tta - sub * 24;
        const int bn  = bn0 + sub;
        const int b   = bn / 1000, n = bn - b * 1000;
        const float4 v = *(const float4*)&future_met[((((b * 24 + tt) * 1000) + n) << 4) + f0];
        ushort2 lo = pk_bf16(v.x, v.y), hi = pk_bf16(v.z, v.w);
        ushort4 o; o.x = lo.x; o.y = lo.y; o.z = hi.x; o.w = hi.y;
        *(ushort4*)&fmA[row * FMS + f0] = o;
    }
    {
        const int row = tid >> 3, k = 16 + ((tid & 7) << 1);
        *(unsigned int*)&fmA[row * FMS + k] = 0u;
    }
    __syncthreads();

    const int dlo = qr << 2;
    const int slo = ((tt0 + dlo) >= 24) + ((tt0 + dlo) >= 48);
    const int shi = ((tt0 + dlo + 19) >= 24) + ((tt0 + dlo + 19) >= 48);
    float flo[4], fhi[4];
    {
        const float* fhl = final_h + ((bn0 + slo) << 8) + (w << 6) + col;
        const float* fhh = final_h + ((bn0 + shi) << 8) + (w << 6) + col;
        #pragma unroll
        for (int j = 0; j < 4; ++j) { flo[j] = fhl[j << 4]; fhi[j] = fhh[j << 4]; }
    }

    f32x4 acc[2][4];
    #pragma unroll
    for (int i = 0; i < 2; ++i) {
        #pragma unroll
        for (int r = 0; r < 4; ++r) {
            const int d   = (i << 4) + (qr << 2) + r;
            const int tta = tt0 + d;
            const int sub = (tta >= 24) + (tta >= 48);
            const int tt  = tta - sub * 24;
            const bool lo = (sub == slo);
            const float4 sb4 = *(const float4*)&sqb[(tt << 8) + fb];
            acc[i][0][r] = (lo ? flo[0] : fhi[0]) + sb4.x;
            acc[i][1][r] = (lo ? flo[1] : fhi[1]) + sb4.y;
            acc[i][2][r] = (lo ? flo[2] : fhi[2]) + sb4.z;
            acc[i][3][r] = (lo ? flo[3] : fhi[3]) + sb4.w;
        }
    }
    {
        const bf16x8 af0 = *(const bf16x8*)&fmA[col * FMS + (qr << 3)];
        const bf16x8 af1 = *(const bf16x8*)&fmA[(16 + col) * FMS + (qr << 3)];
        const unsigned short* Bwf = wfmfrag + (w << 11) + (l << 3);
        #pragma unroll
        for (int j = 0; j < 4; ++j) {
            const bf16x8 bf = *(const bf16x8*)(Bwf + (j << 9));
            acc[0][j] = __builtin_amdgcn_mfma_f32_16x16x32_bf16(af0, bf, acc[0][j], 0, 0, 0);
            acc[1][j] = __builtin_amdgcn_mfma_f32_16x16x32_bf16(af1, bf, acc[1][j], 0, 0, 0);
        }
    }

    #pragma unroll
    for (int i = 0; i < 2; ++i) {
        #pragma unroll
        for (int r = 0; r < 4; ++r) {
            const int m = (i << 4) + (qr << 2) + r;
            const f32x2 vA = {acc[i][0][r], acc[i][1][r]};
            const f32x2 vB = {acc[i][2][r], acc[i][3][r]};
            const f32x2 sv = vA + vB;
            const f32x2 qv = vA * vA + vB * vB;
            float s = sv.x + sv.y;
            float q = qv.x + qv.y;
            const ushort2 p01 = pk_bf16(vA.x, vA.y);
            const ushort2 p23 = pk_bf16(vB.x, vB.y);
            s = dpp_rowsum(s);
            q = dpp_rowsum(q);
            if (col == 15) red[w][m] = make_float2(s, q);
            ushort4 o; o.x = p01.x; o.y = p01.y; o.z = p23.x; o.w = p23.y;
            *(ushort4*)&Abuf[m * LDA + (w << 6) + (col << 2)] = o;
        }
    }
    __syncthreads();

    if (tid < MROWS) {
        const float2 a0 = red[0][tid], a1 = red[1][tid], a2 = red[2][tid], a3 = red[3][tid];
        const float S = a0.x + a1.x + a2.x + a3.x;
        const float Q = a0.y + a1.y + a2.y + a3.y;
        const float mu = S * 0.00390625f;
        const float rstd = rsqrtf(Q * 0.00390625f - mu * mu + 1e-5f);
        mv[tid] = make_float2(mu, rstd);
    }

    #pragma unroll
    for (int i = 0; i < 2; ++i)
        #pragma unroll
        for (int j = 0; j < 4; ++j)
            acc[i][j] = (f32x4){0.f, 0.f, 0.f, 0.f};

    {
        const unsigned short* Bw  = w1frag + (w << 14) + (l << 3);
        const unsigned short* Ab0 = &Abuf[col * LDA + (qr << 3)];
        const unsigned short* Ab1 = &Abuf[(16 + col) * LDA + (qr << 3)];
        #pragma unroll
        for (int kk = 0; kk < 8; ++kk) {
            const bf16x8 a0 = *(const bf16x8*)(Ab0 + (kk << 5));
            const bf16x8 a1 = *(const bf16x8*)(Ab1 + (kk << 5));
            #pragma unroll
            for (int j = 0; j < 4; ++j) {
                const bf16x8 bf = *(const bf16x8*)(Bw + (j << 12) + (kk << 9));
                acc[0][j] = __builtin_amdgcn_mfma_f32_16x16x32_bf16(a0, bf, acc[0][j], 0, 0, 0);
                acc[1][j] = __builtin_amdgcn_mfma_f32_16x16x32_bf16(a1, bf, acc[1][j], 0, 0, 0);
            }
        }
    }

    const float4 gw4 = *(const float4*)&gw1f[fb];
    const float4 bt4 = *(const float4*)&b1tf[fb];
    const float4 w24 = *(const float4*)&w2f[fb];
    const f32x2 gwA = {gw4.x, gw4.y}, gwB = {gw4.z, gw4.w};
    const f32x2 btA = {bt4.x, bt4.y}, btB = {bt4.z, bt4.w};
    const f32x2 w2A = {w24.x, w24.y}, w2B = {w24.z, w24.w};
    __syncthreads();

    #pragma unroll
    for (int i = 0; i < 2; ++i) {
        #pragma unroll
        for (int r = 0; r < 4; ++r) {
            const int m = (i << 4) + (qr << 2) + r;
            const float2 p = mv[m];
            const float cm = -p.x * p.y;
            const f32x2 baseA = gwA * cm + btA;
            const f32x2 baseB = gwB * cm + btB;
            const f32x2 accA = {acc[i][0][r], acc[i][1][r]};
            const f32x2 accB = {acc[i][2][r], acc[i][3][r]};
            const f32x2 yA = accA * p.y + baseA;
            const f32x2 yB = accB * p.y + baseB;
            const f32x2 gvA = gelu_fast2(yA);
            const f32x2 gvB = gelu_fast2(yB);
            const f32x2 pp2 = gvA * w2A + gvB * w2B;
            float pp = pp2.x + pp2.y;
            pp = dpp_rowsum(pp);
            if (col == 15) part[w][m] = pp;
        }
    }
    __syncthreads();

    if (tid < MROWS) {
        const int m = m0 + tid;
        const float val = part[0][tid] + part[1][tid] + part[2][tid] + part[3][tid] + b2[0];
        const int bn = m / 24, tt = m - bn * 24;
        const int b  = bn / 1000, n = bn - b * 1000;
        out[(b * 24 + tt) * 1000 + n] = val;
    }
}

extern "C" void kernel_launch(void* const* d_in, const int* in_sizes, int n_in,
                              void* d_out, int out_size, void* d_ws, size_t ws_size,
                              hipStream_t stream) {
    const float* final_h    = (const float*)d_in[0];
    const float* future_met = (const float*)d_in[1];
    const float* step_q     = (const float*)d_in[2];
    const float* W_fm       = (const float*)d_in[3];
    const float* b_fm       = (const float*)d_in[4];
    const float* gamma      = (const float*)d_in[5];
    const float* beta       = (const float*)d_in[6];
    const float* W1         = (const float*)d_in[7];
    const float* b1         = (const float*)d_in[8];
    const float* W2         = (const float*)d_in[9];
    const float* b2         = (const float*)d_in[10];

    char* ws = (char*)d_ws;
    unsigned short* w1frag  = (unsigned short*)(ws);                //  131072 B
    float*          sqb     = (float*)(ws + 131072);                //   24576 B
    unsigned short* wfmfrag = (unsigned short*)(ws + 155648);       //   16384 B
    float*          gpart   = (float*)(ws + 172032);                //    8192 B
    float*          bpart   = (float*)(ws + 180224);                //    8192 B
    float*          gw1f    = (float*)(ws + 188416);                //    1024 B
    float*          b1tf    = (float*)(ws + 189440);                //    1024 B
    float*          w2f     = (float*)(ws + 190464);                //    1024 B
    float*          WFWp    = (float*)(ws + 191488);                //   16384 B
    float*          SQWp    = (float*)(ws + 207872);                //   24576 B
    unsigned short* wfwfrag = (unsigned short*)(ws + 232448);       //   16384 B
    float*          sqwf    = (float*)(ws + 248832);                //   24576 B
    float*          FHW     = (float*)(ws + 274432);                // 16384000 B
    float* out = (float*)d_out;

    const size_t WS_NEEDED = 274432u + 16384000u;
    if (ws_size >= WS_NEEDED) {
        prep1<<<44, 256, 0, stream>>>(W1, step_q, b_fm, W_fm, gamma, beta,
                                      w1frag, sqb, wfmfrag, gpart, bpart, WFWp, SQWp);
        prep3<<<1001, 256, 0, stream>>>(final_h, w1frag, gpart, bpart, b1, W2,
                                        WFWp, SQWp, gw1f, b1tf, w2f,
                                        wfwfrag, sqwf, FHW);
        fused_head<<<12000, 256, 0, stream>>>(final_h, future_met, b2, sqb, wfmfrag,
                                              gw1f, b1tf, w2f, wfwfrag, sqwf, FHW, out);
    } else {
        prep1<<<36, 256, 0, stream>>>(W1, step_q, b_fm, W_fm, gamma, beta,
                                      w1frag, sqb, wfmfrag, gpart, bpart, WFWp, SQWp);
        prep2<<<1, 256, 0, stream>>>(gpart, bpart, b1, W2, gw1f, b1tf, w2f);
        fused_head_v3<<<12000, 256, 0, stream>>>(final_h, future_met, b2, w1frag, sqb,
                                                 wfmfrag, gw1f, b1tf, w2f, out);
    }
}

// Round 11
// 209.612 us; speedup vs baseline: 1.1597x; 1.0809x over previous
//
#include <hip/hip_runtime.h>
#include <hip/hip_bf16.h>
#include <stdint.h>

#define MROWS 32
#define LDA   264   // Abuf stride in bf16 elems: 528 B/row (16B-aligned, bank-skewed)
#define FMS   40    // fmA stride in bf16 elems (80 B, 16B-aligned)

typedef __bf16 bf16x8 __attribute__((ext_vector_type(8)));
typedef float  f32x4  __attribute__((ext_vector_type(4)));
typedef float  f32x2  __attribute__((ext_vector_type(2)));

__device__ __forceinline__ unsigned short f2bf(float f) {
    union { float f; uint32_t u; } v; v.f = f;
    return (unsigned short)((v.u + 0x7FFFu + ((v.u >> 16) & 1u)) >> 16);
}

__device__ __forceinline__ ushort2 pk_bf16(float a, float b) {
    union { __hip_bfloat162 v; ushort2 u; } c;
    c.v = __float22bfloat162_rn(make_float2(a, b));
    return c.u;
}

// DPP row-reduction step on the VALU pipe (no DS): x += row_shr<N>(x),
// bound_ctrl=1 -> cross-row sources read 0 (sum identity). After steps
// 1,2,4,8 lane col==15 of each 16-lane row holds the full row sum.
template <int CTRL>
__device__ __forceinline__ float dpp_radd(float x) {
    union { float f; int i; } a, b;
    a.f = x;
    b.i = __builtin_amdgcn_update_dpp(0, a.i, CTRL, 0xF, 0xF, true);
    return x + b.f;
}
#define ROW_SHR1 0x111
#define ROW_SHR2 0x112
#define ROW_SHR4 0x114
#define ROW_SHR8 0x118
__device__ __forceinline__ float dpp_rowsum(float x) {
    x = dpp_radd<ROW_SHR1>(x);
    x = dpp_radd<ROW_SHR2>(x);
    x = dpp_radd<ROW_SHR4>(x);
    x = dpp_radd<ROW_SHR8>(x);
    return x;   // valid in lane col==15 of each row
}

// tanh-form GeLU via sigmoid on a float2 pair; muls/fmas lower to v_pk_* VOP3P.
__device__ __forceinline__ f32x2 gelu_fast2(f32x2 v) {
    const f32x2 t = v * v;
    f32x2 p = t * 0.044715f + 1.0f;
    const f32x2 u = v * p;
    f32x2 e;
    e.x = __builtin_amdgcn_exp2f(u.x * -2.3021131160186336f);  // exp(-2*0.79788456*u)
    e.y = __builtin_amdgcn_exp2f(u.y * -2.3021131160186336f);
    f32x2 r;
    r.x = __builtin_amdgcn_rcpf(1.0f + e.x);
    r.y = __builtin_amdgcn_rcpf(1.0f + e.y);
    return v * r;
}

// Fragment-order POSITION -> LOGICAL map: position f = w*64 + col*4 + j holds
// logical n = w*64 + j*16 + col.  NOT an involution.
__device__ __forceinline__ int frag_n(int f) {
    return (f & 0xC0) | ((f & 3) << 4) | ((f >> 2) & 15);
}

// ============================================================================
// prep_all (37 blocks, ONE launch, all sub-tasks dependency-free):
//  blk 0..7 : w1frag (k-permuted, gamma-folded bf16 W1 fragments) — r3-proven
//             body minus the gpart/bpart partial sums (no longer needed).
//  blk 8..31: sqb[t] = step_q[t] + b_fm (fragment order, gather) — r3 verbatim
//  blk 32..35: wfmfrag (W_fm B-fragments, K=16 zero-padded) — r3 verbatim
//  blk 36   : gw1f/b1tf/w2f by DIRECT colsum (r9-harness-verified pattern;
//             replaces the gpart/bpart reduction + separate prep2 launch).
// ============================================================================
__global__ __launch_bounds__(256) void prep_all(const float* __restrict__ W1,
                                                const float* __restrict__ step_q,
                                                const float* __restrict__ b_fm,
                                                const float* __restrict__ W_fm,
                                                const float* __restrict__ gamma,
                                                const float* __restrict__ beta,
                                                const float* __restrict__ b1,
                                                const float* __restrict__ W2,
                                                unsigned short* __restrict__ w1frag,
                                                float* __restrict__ sqb,
                                                unsigned short* __restrict__ wfmfrag,
                                                float* __restrict__ gw1f,
                                                float* __restrict__ b1tf,
                                                float* __restrict__ w2f) {
    __shared__ unsigned short T[256][40];   // [n][k_local], rows 80B (16B-aligned)
    const int blk = blockIdx.x, tid = threadIdx.x;
    if (blk < 8) {
        const int kk = blk;
        #pragma unroll
        for (int r = 0; r < 32; ++r) {
            const int klog = frag_n((kk << 5) + r);    // logical k for k-position kk*32+r
            const float wv = W1[klog * 256 + tid];     // coalesced row read (row uniform)
            T[tid][r] = f2bf(wv * gamma[klog]);        // gamma folded into W1
        }
        __syncthreads();
        #pragma unroll
        for (int f = 0; f < 4; ++f) {
            const int fi = (f << 8) + tid;             // 0..1023 = w*256 + j*64 + l
            const int l = fi & 63, j = (fi >> 6) & 3, w = fi >> 8;
            const int n = (w << 6) + (j << 4) + (l & 15);
            const uint4 v = *(const uint4*)&T[n][(l >> 4) << 3];  // 8 contiguous bf16
            *(uint4*)&w1frag[((w << 5) + (j << 3) + kk) * 512 + (l << 3)] = v;
        }
    } else if (blk < 32) {
        const int t = blk - 8;
        const int n = frag_n(tid);
        sqb[t * 256 + tid] = step_q[t * 256 + n] + b_fm[n];
    } else if (blk < 36) {
        const int f  = blk - 32;                       // 0..3
        const int fr = (f << 8) + tid;
        const int l = fr & 63, j = (fr >> 6) & 3, w = fr >> 8;
        const int n = (w << 6) + (j << 4) + (l & 15);
        const int qr = l >> 4;
        #pragma unroll
        for (int e = 0; e < 8; ++e) {
            const int k = (qr << 3) + e;
            wfmfrag[(fr << 3) + e] = (k < 16) ? f2bf(W_fm[(k << 8) + n]) : (unsigned short)0;
        }
    } else {
        // direct colsum (gather: read logical n = frag_n(tid), store at tid) —
        // verified on hardware in r9's prep_all blk 528.
        const int n = frag_n(tid);
        float sg = 0.f, sb = 0.f;
        for (int k = 0; k < 256; ++k) {
            const float wv = W1[(k << 8) + n];
            sg = fmaf(gamma[k], wv, sg);
            sb = fmaf(beta[k],  wv, sb);
        }
        gw1f[tid] = sg;
        b1tf[tid] = sb + b1[n];
        w2f[tid]  = W2[n];
    }
}

// ============================================================================
// fused_head — r3-PASSING VERBATIM (124 us, absmax 0.0039). In-kernel Abuf
// K=256 GEMM; FHW precompute was measured NET-NEGATIVE (r10: −6 us here,
// +33 us prep). NOTE: __launch_bounds__(256,6) is load-bearing — (256,4)
// corrupted results in r6/r7/r8 (confirmed A/B vs r5/r9). Do not change.
// ============================================================================
__global__ __launch_bounds__(256, 6) void fused_head(
    const float* __restrict__ final_h, const float* __restrict__ future_met,
    const float* __restrict__ b2,      const unsigned short* __restrict__ w1frag,
    const float* __restrict__ sqb,     const unsigned short* __restrict__ wfmfrag,
    const float* __restrict__ gw1f,    const float* __restrict__ b1tf,
    const float* __restrict__ w2f,     float* __restrict__ out)
{
    __shared__ __align__(16) unsigned short Abuf[MROWS * LDA];
    __shared__ __align__(16) unsigned short fmA[MROWS * FMS];
    __shared__ float2 red[4][MROWS];
    __shared__ float2 mv[MROWS];
    __shared__ float  part[4][MROWS];

    const int tid = threadIdx.x;
    const int w   = tid >> 6;
    const int l   = tid & 63;
    const int col = l & 15;
    const int qr  = l >> 4;
    const int m0  = blockIdx.x * MROWS;
    const int bn0 = m0 / 24;
    const int tt0 = m0 - bn0 * 24;
    const int fb  = (w << 6) + (col << 2);

    if (tid < 128) {
        const int row = tid >> 2, f0 = (tid & 3) << 2;
        const int tta = tt0 + row;
        const int sub = (tta >= 24) + (tta >= 48);
        const int tt  = tta - sub * 24;
        const int bn  = bn0 + sub;
        const int b   = bn / 1000, n = bn - b * 1000;
        const float4 v = *(const float4*)&future_met[((((b * 24 + tt) * 1000) + n) << 4) + f0];
        ushort2 lo = pk_bf16(v.x, v.y), hi = pk_bf16(v.z, v.w);
        ushort4 o; o.x = lo.x; o.y = lo.y; o.z = hi.x; o.w = hi.y;
        *(ushort4*)&fmA[row * FMS + f0] = o;
    }
    {
        const int row = tid >> 3, k = 16 + ((tid & 7) << 1);
        *(unsigned int*)&fmA[row * FMS + k] = 0u;
    }
    __syncthreads();

    const int dlo = qr << 2;
    const int slo = ((tt0 + dlo) >= 24) + ((tt0 + dlo) >= 48);
    const int shi = ((tt0 + dlo + 19) >= 24) + ((tt0 + dlo + 19) >= 48);
    float flo[4], fhi[4];
    {
        const float* fhl = final_h + ((bn0 + slo) << 8) + (w << 6) + col;
        const float* fhh = final_h + ((bn0 + shi) << 8) + (w << 6) + col;
        #pragma unroll
        for (int j = 0; j < 4; ++j) { flo[j] = fhl[j << 4]; fhi[j] = fhh[j << 4]; }
    }

    f32x4 acc[2][4];
    #pragma unroll
    for (int i = 0; i < 2; ++i) {
        #pragma unroll
        for (int r = 0; r < 4; ++r) {
            const int d   = (i << 4) + (qr << 2) + r;
            const int tta = tt0 + d;
            const int sub = (tta >= 24) + (tta >= 48);
            const int tt  = tta - sub * 24;
            const bool lo = (sub == slo);
            const float4 sb4 = *(const float4*)&sqb[(tt << 8) + fb];
            acc[i][0][r] = (lo ? flo[0] : fhi[0]) + sb4.x;
            acc[i][1][r] = (lo ? flo[1] : fhi[1]) + sb4.y;
            acc[i][2][r] = (lo ? flo[2] : fhi[2]) + sb4.z;
            acc[i][3][r] = (lo ? flo[3] : fhi[3]) + sb4.w;
        }
    }
    {
        const bf16x8 af0 = *(const bf16x8*)&fmA[col * FMS + (qr << 3)];
        const bf16x8 af1 = *(const bf16x8*)&fmA[(16 + col) * FMS + (qr << 3)];
        const unsigned short* Bwf = wfmfrag + (w << 11) + (l << 3);
        #pragma unroll
        for (int j = 0; j < 4; ++j) {
            const bf16x8 bf = *(const bf16x8*)(Bwf + (j << 9));
            acc[0][j] = __builtin_amdgcn_mfma_f32_16x16x32_bf16(af0, bf, acc[0][j], 0, 0, 0);
            acc[1][j] = __builtin_amdgcn_mfma_f32_16x16x32_bf16(af1, bf, acc[1][j], 0, 0, 0);
        }
    }

    // stats (DPP row-sum, raw x) + packed b64 A-tile store (frag-permuted;
    // w1frag rows pre-permuted by the same map, so the GEMM is invariant).
    #pragma unroll
    for (int i = 0; i < 2; ++i) {
        #pragma unroll
        for (int r = 0; r < 4; ++r) {
            const int m = (i << 4) + (qr << 2) + r;
            const f32x2 vA = {acc[i][0][r], acc[i][1][r]};
            const f32x2 vB = {acc[i][2][r], acc[i][3][r]};
            const f32x2 sv = vA + vB;
            const f32x2 qv = vA * vA + vB * vB;
            float s = sv.x + sv.y;
            float q = qv.x + qv.y;
            const ushort2 p01 = pk_bf16(vA.x, vA.y);
            const ushort2 p23 = pk_bf16(vB.x, vB.y);
            s = dpp_rowsum(s);
            q = dpp_rowsum(q);
            if (col == 15) red[w][m] = make_float2(s, q);
            ushort4 o; o.x = p01.x; o.y = p01.y; o.z = p23.x; o.w = p23.y;
            *(ushort4*)&Abuf[m * LDA + (w << 6) + (col << 2)] = o;
        }
    }
    __syncthreads();

    if (tid < MROWS) {
        const float2 a0 = red[0][tid], a1 = red[1][tid], a2 = red[2][tid], a3 = red[3][tid];
        const float S = a0.x + a1.x + a2.x + a3.x;
        const float Q = a0.y + a1.y + a2.y + a3.y;
        const float mu = S * 0.00390625f;
        const float rstd = rsqrtf(Q * 0.00390625f - mu * mu + 1e-5f);
        mv[tid] = make_float2(mu, rstd);
    }

    #pragma unroll
    for (int i = 0; i < 2; ++i)
        #pragma unroll
        for (int j = 0; j < 4; ++j)
            acc[i][j] = (f32x4){0.f, 0.f, 0.f, 0.f};

    {
        const unsigned short* Bw  = w1frag + (w << 14) + (l << 3);
        const unsigned short* Ab0 = &Abuf[col * LDA + (qr << 3)];
        const unsigned short* Ab1 = &Abuf[(16 + col) * LDA + (qr << 3)];
        #pragma unroll
        for (int kk = 0; kk < 8; ++kk) {
            const bf16x8 a0 = *(const bf16x8*)(Ab0 + (kk << 5));
            const bf16x8 a1 = *(const bf16x8*)(Ab1 + (kk << 5));
            #pragma unroll
            for (int j = 0; j < 4; ++j) {
                const bf16x8 bf = *(const bf16x8*)(Bw + (j << 12) + (kk << 9));
                acc[0][j] = __builtin_amdgcn_mfma_f32_16x16x32_bf16(a0, bf, acc[0][j], 0, 0, 0);
                acc[1][j] = __builtin_amdgcn_mfma_f32_16x16x32_bf16(a1, bf, acc[1][j], 0, 0, 0);
            }
        }
    }

    const float4 gw4 = *(const float4*)&gw1f[fb];
    const float4 bt4 = *(const float4*)&b1tf[fb];
    const float4 w24 = *(const float4*)&w2f[fb];
    const f32x2 gwA = {gw4.x, gw4.y}, gwB = {gw4.z, gw4.w};
    const f32x2 btA = {bt4.x, bt4.y}, btB = {bt4.z, bt4.w};
    const f32x2 w2A = {w24.x, w24.y}, w2B = {w24.z, w24.w};
    __syncthreads();

    #pragma unroll
    for (int i = 0; i < 2; ++i) {
        #pragma unroll
        for (int r = 0; r < 4; ++r) {
            const int m = (i << 4) + (qr << 2) + r;
            const float2 p = mv[m];
            const float cm = -p.x * p.y;
            const f32x2 baseA = gwA * cm + btA;
            const f32x2 baseB = gwB * cm + btB;
            const f32x2 accA = {acc[i][0][r], acc[i][1][r]};
            const f32x2 accB = {acc[i][2][r], acc[i][3][r]};
            const f32x2 yA = accA * p.y + baseA;
            const f32x2 yB = accB * p.y + baseB;
            const f32x2 gvA = gelu_fast2(yA);
            const f32x2 gvB = gelu_fast2(yB);
            const f32x2 pp2 = gvA * w2A + gvB * w2B;
            float pp = pp2.x + pp2.y;
            pp = dpp_rowsum(pp);
            if (col == 15) part[w][m] = pp;
        }
    }
    __syncthreads();

    if (tid < MROWS) {
        const int m = m0 + tid;
        const float val = part[0][tid] + part[1][tid] + part[2][tid] + part[3][tid] + b2[0];
        const int bn = m / 24, tt = m - bn * 24;
        const int b  = bn / 1000, n = bn - b * 1000;
        out[(b * 24 + tt) * 1000 + n] = val;
    }
}

extern "C" void kernel_launch(void* const* d_in, const int* in_sizes, int n_in,
                              void* d_out, int out_size, void* d_ws, size_t ws_size,
                              hipStream_t stream) {
    const float* final_h    = (const float*)d_in[0];
    const float* future_met = (const float*)d_in[1];
    const float* step_q     = (const float*)d_in[2];
    const float* W_fm       = (const float*)d_in[3];
    const float* b_fm       = (const float*)d_in[4];
    const float* gamma      = (const float*)d_in[5];
    const float* beta       = (const float*)d_in[6];
    const float* W1         = (const float*)d_in[7];
    const float* b1         = (const float*)d_in[8];
    const float* W2         = (const float*)d_in[9];
    const float* b2         = (const float*)d_in[10];
    float* out = (float*)d_out;
    char* ws = (char*)d_ws;

    unsigned short* w1frag  = (unsigned short*)(ws);                //  131072 B
    float*          sqb     = (float*)(ws + 131072);                //   24576 B
    unsigned short* wfmfrag = (unsigned short*)(ws + 155648);       //   16384 B
    float*          gw1f    = (float*)(ws + 172032);                //    1024 B
    float*          b1tf    = (float*)(ws + 173056);                //    1024 B
    float*          w2f     = (float*)(ws + 174080);                //    1024 B

    prep_all<<<37, 256, 0, stream>>>(W1, step_q, b_fm, W_fm, gamma, beta, b1, W2,
                                     w1frag, sqb, wfmfrag, gw1f, b1tf, w2f);
    fused_head<<<12000, 256, 0, stream>>>(final_h, future_met, b2, w1frag, sqb,
                                          wfmfrag, gw1f, b1tf, w2f, out);
}